// Round 1
// baseline (229.229 us; speedup 1.0000x reference)
//
#include <hip/hip_runtime.h>

#define EPS 1e-5f
#define SLOPE 0.2f

// LayerNorm + LeakyReLU over N register-resident elements (per-thread row).
template<int N>
__device__ __forceinline__ void ln_lrelu(float* h, const float* __restrict__ g,
                                         const float* __restrict__ b) {
  float m = 0.f;
#pragma unroll
  for (int j = 0; j < N; ++j) m += h[j];
  m *= (1.0f / N);
  float v = 0.f;
#pragma unroll
  for (int j = 0; j < N; ++j) { float d = h[j] - m; v = fmaf(d, d, v); }
  v *= (1.0f / N);
  float rs = rsqrtf(v + EPS);
#pragma unroll
  for (int j = 0; j < N; ++j) {
    float t = (h[j] - m) * rs * g[j] + b[j];
    h[j] = t > 0.f ? t : SLOPE * t;
  }
}

// hout[j] = sum_k hin[k] * W[k*DOUT + j]; W accesses are wave-uniform -> s_load.
template<int DIN, int DOUT>
__device__ __forceinline__ void linear(const float* hin, float* hout,
                                       const float* __restrict__ W) {
#pragma unroll
  for (int j = 0; j < DOUT; ++j) hout[j] = 0.f;
#pragma unroll
  for (int k = 0; k < DIN; ++k) {
    float hk = hin[k];
#pragma unroll
    for (int j = 0; j < DOUT; ++j) hout[j] = fmaf(hk, W[k * DOUT + j], hout[j]);
  }
}

__global__ __launch_bounds__(256) void disc_fused(
    const float* __restrict__ x,
    const float* __restrict__ W1, const float* __restrict__ g1, const float* __restrict__ b1,
    const float* __restrict__ W2, const float* __restrict__ g2, const float* __restrict__ b2,
    const float* __restrict__ W3, const float* __restrict__ g3, const float* __restrict__ b3,
    const float* __restrict__ W4, const float* __restrict__ g4, const float* __restrict__ b4,
    const float* __restrict__ W5, const float* __restrict__ g5, const float* __restrict__ b5,
    const float* __restrict__ W6, const float* __restrict__ g6, const float* __restrict__ b6,
    const float* __restrict__ W7, const float* __restrict__ g7, const float* __restrict__ b7,
    const float* __restrict__ W8, const float* __restrict__ b8,
    float* __restrict__ out, int nrows) {
  // x tile staged through LDS: [256 rows][32 cols chunk], pad 33 -> 2-way banks (free).
  __shared__ float xs[256][33];
  const int t = threadIdx.x;
  const long row0 = (long)blockIdx.x * 256;
  const long nmax = (long)nrows - 1;

  float h1[32];
#pragma unroll
  for (int j = 0; j < 32; ++j) h1[j] = 0.f;

  const float4* __restrict__ x4 = reinterpret_cast<const float4*>(x);
  for (int c = 0; c < 4; ++c) {  // 4 chunks of 32 columns
    if (c) __syncthreads();
#pragma unroll
    for (int q = 0; q < 8; ++q) {
      int f = q * 256 + t;
      int r = f >> 3, c4 = f & 7;
      long rr = row0 + r; if (rr > nmax) rr = nmax;
      float4 v = x4[rr * 32 + c * 8 + c4];  // contiguous 128B per 8-lane group
      xs[r][c4 * 4 + 0] = v.x;
      xs[r][c4 * 4 + 1] = v.y;
      xs[r][c4 * 4 + 2] = v.z;
      xs[r][c4 * 4 + 3] = v.w;
    }
    __syncthreads();
    // rolled k-loop: 1 ds_read + 32 FMA (weights via s_load) per k
    for (int k = 0; k < 32; ++k) {
      float xk = xs[t][k];
      const float* __restrict__ wrow = &W1[(c * 32 + k) * 32];
#pragma unroll
      for (int j = 0; j < 32; ++j) h1[j] = fmaf(xk, wrow[j], h1[j]);
    }
  }
  ln_lrelu<32>(h1, g1, b1);

  float h2[64]; linear<32, 64>(h1, h2, W2); ln_lrelu<64>(h2, g2, b2);
  float h3[32]; linear<64, 32>(h2, h3, W3); ln_lrelu<32>(h3, g3, b3);
  float h4[16]; linear<32, 16>(h3, h4, W4); ln_lrelu<16>(h4, g4, b4);
  float h5[8];  linear<16, 8>(h4, h5, W5);  ln_lrelu<8>(h5, g5, b5);
  float h6[4];  linear<8, 4>(h5, h6, W6);   ln_lrelu<4>(h6, g6, b6);
  float h7[2];  linear<4, 2>(h6, h7, W7);   ln_lrelu<2>(h7, g7, b7);

  float o = fmaf(h7[1], W8[1], fmaf(h7[0], W8[0], b8[0]));
  long row = row0 + t;
  if (row < (long)nrows) out[row] = o;
}

extern "C" void kernel_launch(void* const* d_in, const int* in_sizes, int n_in,
                              void* d_out, int out_size, void* d_ws, size_t ws_size,
                              hipStream_t stream) {
  const float* x  = (const float*)d_in[0];
  const float* W1 = (const float*)d_in[1];
  const float* g1 = (const float*)d_in[2];
  const float* b1 = (const float*)d_in[3];
  const float* W2 = (const float*)d_in[4];
  const float* g2 = (const float*)d_in[5];
  const float* b2 = (const float*)d_in[6];
  const float* W3 = (const float*)d_in[7];
  const float* g3 = (const float*)d_in[8];
  const float* b3 = (const float*)d_in[9];
  const float* W4 = (const float*)d_in[10];
  const float* g4 = (const float*)d_in[11];
  const float* b4 = (const float*)d_in[12];
  const float* W5 = (const float*)d_in[13];
  const float* g5 = (const float*)d_in[14];
  const float* b5 = (const float*)d_in[15];
  const float* W6 = (const float*)d_in[16];
  const float* g6 = (const float*)d_in[17];
  const float* b6 = (const float*)d_in[18];
  const float* W7 = (const float*)d_in[19];
  const float* g7 = (const float*)d_in[20];
  const float* b7 = (const float*)d_in[21];
  const float* W8 = (const float*)d_in[22];
  const float* b8 = (const float*)d_in[23];
  float* out = (float*)d_out;

  const int nrows = in_sizes[0] / 128;          // 524288
  const int grid = (nrows + 255) / 256;         // 2048
  hipLaunchKernelGGL(disc_fused, dim3(grid), dim3(256), 0, stream,
                     x, W1, g1, b1, W2, g2, b2, W3, g3, b3, W4, g4, b4,
                     W5, g5, b5, W6, g6, b6, W7, g7, b7, W8, b8, out, nrows);
}